// Round 1
// baseline (407.115 us; speedup 1.0000x reference)
//
#include <hip/hip_runtime.h>
#include <hip/hip_bf16.h>

// Problem: out[s,:] = sum_{i in segment s} (input[i,:] @ W^T + b)
// N = 500000, S = 10000, D_IN = D_OUT = 128.
// Key algebraic transform: segment-sum FIRST (linear op commutes):
//   out[s] = (sum_i X[i]) @ W^T + count_s * b
// Phase 1: segment-sum X (N x 128 -> S x 128), HBM-bound (256 MB read).
// Phase 2: tiny GEMM (10000 x 128 x 128) + count*b epilogue.

#define D 128          // D_IN == D_OUT
#define D4 32          // D/4

// ---------------- Phase 1: per-segment row sum ----------------
// One block (128 threads = 2 waves) per segment. Thread layout:
// rg = tid/32 selects row within a 4-row group, c4 = tid%32 selects float4
// column. Each iteration the block reads 4 rows x 512B = 2 KB coalesced.
__global__ __launch_bounds__(128) void seg_sum_kernel(
    const float* __restrict__ in, const int* __restrict__ graph,
    float* __restrict__ Xs, int N, int S) {
  int s   = blockIdx.x;
  int tid = threadIdx.x;
  int rg  = tid >> 5;   // 0..3
  int c4  = tid & 31;   // 0..31

  int rs  = graph[2 * s];
  int re  = graph[2 * s + 1];
  int nxt = (s + 1 < S) ? (graph[2 * s + 2] - 1) : (N - 1);
  re = min(re, min(nxt, N - 1));
  rs = max(rs, 0);
  int cnt = max(0, re - rs + 1);

  const float4* p = (const float4*)in;
  float4 acc = make_float4(0.f, 0.f, 0.f, 0.f);
  for (int r = rg; r < cnt; r += 4) {
    float4 v = p[(rs + r) * D4 + c4];
    acc.x += v.x; acc.y += v.y; acc.z += v.z; acc.w += v.w;
  }

  // reduce the 4 row-groups
  __shared__ float4 red[128];
  red[tid] = acc;
  __syncthreads();
  if (rg == 0) {
    float4 a0 = red[c4];
    float4 a1 = red[32 + c4];
    float4 a2 = red[64 + c4];
    float4 a3 = red[96 + c4];
    float4 r4;
    r4.x = (a0.x + a1.x) + (a2.x + a3.x);
    r4.y = (a0.y + a1.y) + (a2.y + a3.y);
    r4.z = (a0.z + a1.z) + (a2.z + a3.z);
    r4.w = (a0.w + a1.w) + (a2.w + a3.w);
    ((float4*)Xs)[s * D4 + c4] = r4;
  }
}

// ---------------- Phase 2: out = Xs @ W^T + cnt*b ----------------
// Tile: 16 segments x 64 output cols per 256-thread block.
// Wt LDS tile stored transposed [d][o'] with stride 65 (conflict-free
// stride-1 reads across the wave). Xs tile broadcast-read as float4.
#define SEG_PB 16
#define OUT_PB 64
#define WT_STRIDE 65

__global__ __launch_bounds__(256) void seg_gemm_kernel(
    const float* __restrict__ Xs, const float* __restrict__ W,
    const float* __restrict__ b, const int* __restrict__ graph,
    float* __restrict__ out, int N, int S) {
  __shared__ float Wt[D * WT_STRIDE];            // 33.3 KB
  __shared__ __align__(16) float XsL[SEG_PB * D]; // 8 KB
  __shared__ float cntL[SEG_PB];

  int tid   = threadIdx.x;
  int s0    = blockIdx.x * SEG_PB;
  int oBase = blockIdx.y * OUT_PB;

  // stage W^T tile: rows [oBase, oBase+64), coalesced float4 global reads,
  // scalar LDS writes (stride-65 => 4-way conflict, once per block)
  #pragma unroll
  for (int rnd = 0; rnd < 8; ++rnd) {
    int linear = rnd * 256 + tid;        // 0..2047
    int op     = linear >> 5;            // 0..63 local out row
    int d4     = (linear & 31) << 2;     // 0,4,...,124
    float4 w = *(const float4*)(W + (oBase + op) * D + d4);
    Wt[(d4 + 0) * WT_STRIDE + op] = w.x;
    Wt[(d4 + 1) * WT_STRIDE + op] = w.y;
    Wt[(d4 + 2) * WT_STRIDE + op] = w.z;
    Wt[(d4 + 3) * WT_STRIDE + op] = w.w;
  }
  // stage Xs tile: 2048 floats = 512 float4, 2 rounds
  {
    const float4* src = (const float4*)(Xs + s0 * D);
    float4* dst = (float4*)XsL;
    dst[tid]       = src[tid];
    dst[tid + 256] = src[tid + 256];
  }
  // segment counts (replicates reference valid-mask semantics)
  if (tid < SEG_PB) {
    int s   = s0 + tid;
    int rs  = graph[2 * s];
    int re  = graph[2 * s + 1];
    int nxt = (s + 1 < S) ? (graph[2 * s + 2] - 1) : (N - 1);
    re = min(re, min(nxt, N - 1));
    rs = max(rs, 0);
    cntL[tid] = (float)max(0, re - rs + 1);
  }
  __syncthreads();

  int op = tid & 63;   // local out col; whole wave shares g
  int g  = tid >> 6;   // 0..3 segment phase
  float acc[4] = {0.f, 0.f, 0.f, 0.f};

  const float4* xs4 = (const float4*)XsL;
  #pragma unroll 8
  for (int d4 = 0; d4 < D4; ++d4) {
    float w0 = Wt[(4 * d4 + 0) * WT_STRIDE + op];
    float w1 = Wt[(4 * d4 + 1) * WT_STRIDE + op];
    float w2 = Wt[(4 * d4 + 2) * WT_STRIDE + op];
    float w3 = Wt[(4 * d4 + 3) * WT_STRIDE + op];
    #pragma unroll
    for (int j = 0; j < 4; ++j) {
      float4 x = xs4[(4 * j + g) * D4 + d4];  // LDS broadcast
      acc[j] += x.x * w0 + x.y * w1 + x.z * w2 + x.w * w3;
    }
  }

  float bo = b[oBase + op];
  #pragma unroll
  for (int j = 0; j < 4; ++j) {
    int sl = 4 * j + g;
    out[(s0 + sl) * D + oBase + op] = acc[j] + cntL[sl] * bo;
  }
}

extern "C" void kernel_launch(void* const* d_in, const int* in_sizes, int n_in,
                              void* d_out, int out_size, void* d_ws, size_t ws_size,
                              hipStream_t stream) {
  const float* in    = (const float*)d_in[0];
  const int*   graph = (const int*)d_in[1];
  const float* W     = (const float*)d_in[2];
  const float* b     = (const float*)d_in[3];
  float* out = (float*)d_out;

  const int N = in_sizes[0] / D;     // 500000
  const int S = in_sizes[1] / 2;     // 10000

  float* Xs = (float*)d_ws;          // S*128 floats = 5.12 MB scratch

  seg_sum_kernel<<<S, 128, 0, stream>>>(in, graph, Xs, N, S);

  dim3 grid2(S / SEG_PB, D / OUT_PB);  // 625 x 2
  seg_gemm_kernel<<<grid2, 256, 0, stream>>>(Xs, W, b, graph, out, N, S);
}

// Round 2
// 370.747 us; speedup vs baseline: 1.0981x; 1.0981x over previous
//
#include <hip/hip_runtime.h>
#include <hip/hip_bf16.h>

// Problem: out[s,:] = sum_{i in segment s} (input[i,:] @ W^T + b)
// N = 500000, S = 10000, D_IN = D_OUT = 128.
// Algebraic transform (linear ops commute):
//   out[s] = (sum_{i in seg s} X[i]) @ W^T + count_s * b
// Phase 1: segment row-sum of X (N x 128 -> S x 128): HBM-bound, 256 MB read.
// Phase 2: small GEMM (10000 x 128 x 128) + count*b epilogue: ~5 us.

#define D 128          // D_IN == D_OUT
#define D4 32          // D/4

__device__ __forceinline__ void f4add(float4& a, const float4& v) {
  a.x += v.x; a.y += v.y; a.z += v.z; a.w += v.w;
}

// ---------------- Phase 1: per-segment row sum ----------------
// One block (256 threads = 4 waves) per segment.
// rg = tid/32 (0..7) row-group, c4 = tid%32 float4 column.
// Each iteration the block reads 8 rows x 512 B = 4 KB coalesced; the row
// loop is unrolled x2 so each wave keeps 2 independent loads in flight.
__global__ __launch_bounds__(256) void seg_sum_kernel(
    const float* __restrict__ in, const int* __restrict__ graph,
    float* __restrict__ Xs, int N, int S) {
  int s   = blockIdx.x;
  int tid = threadIdx.x;
  int rg  = tid >> 5;   // 0..7
  int c4  = tid & 31;   // 0..31

  int rs  = graph[2 * s];
  int re  = graph[2 * s + 1];
  int nxt = (s + 1 < S) ? (graph[2 * s + 2] - 1) : (N - 1);
  re = min(re, min(nxt, N - 1));
  rs = max(rs, 0);
  int cnt = max(0, re - rs + 1);

  const float4* p = (const float4*)in + (size_t)rs * D4 + c4;
  float4 a0 = make_float4(0.f, 0.f, 0.f, 0.f);
  float4 a1 = make_float4(0.f, 0.f, 0.f, 0.f);

  int r = rg;
  for (; r + 8 < cnt; r += 16) {
    float4 v0 = p[r * D4];
    float4 v1 = p[(r + 8) * D4];
    f4add(a0, v0);
    f4add(a1, v1);
  }
  for (; r < cnt; r += 8) {
    float4 v0 = p[r * D4];
    f4add(a0, v0);
  }
  f4add(a0, a1);

  // reduce the 8 row-groups (tree in LDS)
  __shared__ float4 red[256];
  red[tid] = a0;
  __syncthreads();
  if (tid < 128) { f4add(red[tid], red[tid + 128]); }
  __syncthreads();
  if (tid < 64)  { f4add(red[tid], red[tid + 64]); }
  __syncthreads();
  if (tid < 32) {
    float4 r4 = red[tid];
    f4add(r4, red[tid + 32]);
    ((float4*)Xs)[s * D4 + tid] = r4;
  }
}

// ---------------- Phase 2: out = Xs @ W^T + cnt*b ----------------
// Tile: 16 segments x 64 output cols per 256-thread block.
// Wt LDS tile stored transposed [d][o'] with stride 65 (conflict-free
// stride-1 reads across the wave). Xs tile broadcast-read as float4.
#define SEG_PB 16
#define OUT_PB 64
#define WT_STRIDE 65

__global__ __launch_bounds__(256) void seg_gemm_kernel(
    const float* __restrict__ Xs, const float* __restrict__ W,
    const float* __restrict__ b, const int* __restrict__ graph,
    float* __restrict__ out, int N, int S) {
  __shared__ float Wt[D * WT_STRIDE];             // 33.3 KB
  __shared__ __align__(16) float XsL[SEG_PB * D]; // 8 KB
  __shared__ float cntL[SEG_PB];

  int tid   = threadIdx.x;
  int s0    = blockIdx.x * SEG_PB;
  int oBase = blockIdx.y * OUT_PB;

  // stage W^T tile: rows [oBase, oBase+64), coalesced float4 global reads,
  // scalar LDS writes (stride-65, once per block)
  #pragma unroll
  for (int rnd = 0; rnd < 8; ++rnd) {
    int linear = rnd * 256 + tid;        // 0..2047
    int op     = linear >> 5;            // 0..63 local out row
    int d4     = (linear & 31) << 2;     // 0,4,...,124
    float4 w = *(const float4*)(W + (oBase + op) * D + d4);
    Wt[(d4 + 0) * WT_STRIDE + op] = w.x;
    Wt[(d4 + 1) * WT_STRIDE + op] = w.y;
    Wt[(d4 + 2) * WT_STRIDE + op] = w.z;
    Wt[(d4 + 3) * WT_STRIDE + op] = w.w;
  }
  // stage Xs tile: 2048 floats = 512 float4, 2 rounds
  {
    const float4* src = (const float4*)(Xs + s0 * D);
    float4* dst = (float4*)XsL;
    dst[tid]       = src[tid];
    dst[tid + 256] = src[tid + 256];
  }
  // segment counts (replicates reference valid-mask semantics)
  if (tid < SEG_PB) {
    int s   = s0 + tid;
    int rs  = graph[2 * s];
    int re  = graph[2 * s + 1];
    int nxt = (s + 1 < S) ? (graph[2 * s + 2] - 1) : (N - 1);
    re = min(re, min(nxt, N - 1));
    rs = max(rs, 0);
    cntL[tid] = (float)max(0, re - rs + 1);
  }
  __syncthreads();

  int op = tid & 63;   // local out col; whole wave shares g
  int g  = tid >> 6;   // 0..3 segment phase
  float acc[4] = {0.f, 0.f, 0.f, 0.f};

  const float4* xs4 = (const float4*)XsL;
  #pragma unroll 8
  for (int d4 = 0; d4 < D4; ++d4) {
    float w0 = Wt[(4 * d4 + 0) * WT_STRIDE + op];
    float w1 = Wt[(4 * d4 + 1) * WT_STRIDE + op];
    float w2 = Wt[(4 * d4 + 2) * WT_STRIDE + op];
    float w3 = Wt[(4 * d4 + 3) * WT_STRIDE + op];
    #pragma unroll
    for (int j = 0; j < 4; ++j) {
      float4 x = xs4[(4 * j + g) * D4 + d4];  // LDS broadcast
      acc[j] += x.x * w0 + x.y * w1 + x.z * w2 + x.w * w3;
    }
  }

  float bo = b[oBase + op];
  #pragma unroll
  for (int j = 0; j < 4; ++j) {
    int sl = 4 * j + g;
    out[(s0 + sl) * D + oBase + op] = acc[j] + cntL[sl] * bo;
  }
}

extern "C" void kernel_launch(void* const* d_in, const int* in_sizes, int n_in,
                              void* d_out, int out_size, void* d_ws, size_t ws_size,
                              hipStream_t stream) {
  const float* in    = (const float*)d_in[0];
  const int*   graph = (const int*)d_in[1];
  const float* W     = (const float*)d_in[2];
  const float* b     = (const float*)d_in[3];
  float* out = (float*)d_out;

  const int N = in_sizes[0] / D;     // 500000
  const int S = in_sizes[1] / 2;     // 10000

  float* Xs = (float*)d_ws;          // S*128 floats = 5.12 MB scratch

  seg_sum_kernel<<<S, 256, 0, stream>>>(in, graph, Xs, N, S);

  dim3 grid2(S / SEG_PB, D / OUT_PB);  // 625 x 2
  seg_gemm_kernel<<<grid2, 256, 0, stream>>>(Xs, W, b, graph, out, N, S);
}